// Round 7
// baseline (217.626 us; speedup 1.0000x reference)
//
#include <hip/hip_runtime.h>
#include <math.h>

#define CI   256
#define CO   256
#define HW   56
#define LQ   7
#define BETA 10.0f

typedef __attribute__((ext_vector_type(8)))  short short8;
typedef __attribute__((ext_vector_type(4)))  float f32x4;
typedef __attribute__((ext_vector_type(16))) float f32x16;

__device__ __forceinline__ ushort f2bf(float f) {
    uint u = __float_as_uint(f);
    u += 0x7FFF + ((u >> 16) & 1);
    return (ushort)(u >> 16);
}

#define GLDS(SRC, DST)                                                        \
    __builtin_amdgcn_global_load_lds(                                         \
        (const __attribute__((address_space(1))) void*)(SRC),                 \
        (__attribute__((address_space(3))) void*)(DST), 16, 0, 0)

// ---------------- Kernel 1: soft-quantize weights -> packed bf16 ----------------
// W2 layout: [chunk 8][tap 9][kbq 4][co 256][e 8] bf16  (k = chunk*32 + kbq*8 + e)
__global__ __launch_bounds__(256) void quant_weights(const float* __restrict__ p_c,
                                                     const float* __restrict__ q_level,
                                                     short* __restrict__ W2) {
    int idx = blockIdx.x * 256 + threadIdx.x;  // (co*256+ci)*9 + t
    if (idx >= CO * CI * 9) return;
    int coci = idx / 9;
    int t = idx - coci * 9;
    int co = coci >> 8, ci = coci & 255;
    const float* p = p_c + (size_t)idx * LQ;
    float pv[LQ];
    float ss = 0.f;
#pragma unroll
    for (int l = 0; l < LQ; ++l) { pv[l] = p[l]; ss += pv[l] * pv[l]; }
    float inv = rsqrtf(ss) * BETA;
    float m = -1e30f;
#pragma unroll
    for (int l = 0; l < LQ; ++l) { pv[l] *= inv; m = fmaxf(m, pv[l]); }
    float den = 0.f, num = 0.f;
#pragma unroll
    for (int l = 0; l < LQ; ++l) {
        float e = expf(pv[l] - m);
        den += e;
        num += e * q_level[l];
    }
    int widx = ((((ci >> 5) * 9 + t) * 4 + ((ci >> 3) & 3)) * 2048) + co * 8 + (ci & 7);
    W2[widx] = (short)f2bf(num / den);
}

// ---------------- Pre-pass: NCHW f32 -> padded NHWC bf16, border fused ----------------
__global__ __launch_bounds__(256) void prep_main(const float* __restrict__ x,
                                                 ushort* __restrict__ xt) {
    __shared__ ushort ld[256 * 60];
    const int tid = threadIdx.x;
    const int h = blockIdx.x;   // 0..55
    const int b = blockIdx.y;

    if (h == 0 || h == 55) {
        int rr = (h == 0) ? 0 : 57;
        size_t base = ((size_t)b * 58 + rr) * 58 * 256;
        uint4 z = {0, 0, 0, 0};
        for (int i = tid; i < 58 * 256 / 8; i += 256)
            *(uint4*)&xt[base + (size_t)i * 8] = z;
    }
    if (tid < 64) {
        int col = (tid >> 5) * 57;
        int chk = tid & 31;
        size_t o = (((size_t)b * 58 + h + 1) * 58 + col) * 256 + chk * 8;
        uint4 z = {0, 0, 0, 0};
        *(uint4*)&xt[o] = z;
    }

    const float* xp = x + ((size_t)b * CI) * 3136 + h * HW;
#pragma unroll
    for (int s = 0; s < 14; ++s) {
        int flat = s * 1024 + tid * 4;
        int ci = flat / 56;
        int w  = flat - ci * 56;
        const float4 v = *(const float4*)(xp + (size_t)ci * 3136 + w);
        ushort4 o;
        o.x = f2bf(v.x); o.y = f2bf(v.y); o.z = f2bf(v.z); o.w = f2bf(v.w);
        *(ushort4*)&ld[ci * 60 + w] = o;
    }
    __syncthreads();
    const int w = tid & 63;
    const int wq = tid >> 6;
    if (w < 56) {
        size_t obase = (((size_t)b * 58 + h + 1) * 58 + (w + 1)) * 256;
#pragma unroll
        for (int s = 0; s < 8; ++s) {
            int cig = s * 4 + wq;
            int base = (cig * 8) * 60 + w;
            uint u0 = (uint)ld[base]       | ((uint)ld[base + 60]  << 16);
            uint u1 = (uint)ld[base + 120] | ((uint)ld[base + 180] << 16);
            uint u2 = (uint)ld[base + 240] | ((uint)ld[base + 300] << 16);
            uint u3 = (uint)ld[base + 360] | ((uint)ld[base + 420] << 16);
            uint4 o = {u0, u1, u2, u3};
            *(uint4*)&xt[obase + cig * 8] = o;
        }
    }
}

// ---------------- Kernel 2: implicit-GEMM conv, 32x32x16, 3 waves/SIMD ----------------
// block: 256 thr = 4 waves, each wave owns ONE output row; tile 64co x (4h x 64w)
// wave tile: 64co x 64n via 2x2 frags of 32x32x16; acc = 64 VGPR -> 3 waves/SIMD,
// 3 blocks/CU (LDS 50.7KB), 12 waves/CU.
// LDS layout [r 6][kbq 4][c 66][e8]: granule g=(r*4+kbq)*66+c holds
//   x_t[b][h0+r][min(c,57)][ci0+kbq*8 ..+8].
// Reads: lanes vary c -> consecutive 16B granules -> conflict-free b128 (no swizzle).
// One barrier per chunk; stage(ch+1) issued at chunk top, drained at chunk end.
__global__ __launch_bounds__(256, 3) void conv32(const ushort* __restrict__ xt_g,
                                                 const short* __restrict__ W2,
                                                 float* __restrict__ out) {
    __shared__ __align__(16) ushort Bb[2][12672];  // 2 x 25344 B (1584 granules)

    const int tid  = threadIdx.x;
    const int lane = tid & 63;
    const int wv   = tid >> 6;     // wave id = output row 0..3
    const int l31  = lane & 31;
    const int hi   = lane >> 5;    // k-subgroup within K=16 step

    const int h0  = blockIdx.x * 4;
    const int co0 = blockIdx.y * 64;
    const int b   = blockIdx.z;

    // staging: 1584 granules, 396/wave, 7 insts/wave (last has 12 active lanes)
    int bsrc[7];
#pragma unroll
    for (int s = 0; s < 7; ++s) {
        int gl = s * 64 + lane;
        int g  = wv * 396 + (gl < 396 ? gl : 0);
        int r = g / 264, rem = g - r * 264;
        int kbq = rem / 66, c = rem - kbq * 66;
        int cc = c < 58 ? c : 57;          // c>=58 feeds only masked w>=56
        bsrc[s] = ((b * 58 + h0 + r) * 58 + cc) * 256 + kbq * 8;
    }

    f32x16 acc[2][2];
#pragma unroll
    for (int a = 0; a < 2; ++a)
#pragma unroll
        for (int f = 0; f < 2; ++f)
#pragma unroll
            for (int j = 0; j < 16; ++j) acc[a][f][j] = 0.f;

#define STAGE(CH)                                                     \
    {                                                                 \
        const ushort* sp_ = xt_g + (CH) * 32;                         \
        ushort* lb_ = &Bb[(CH) & 1][wv * 396 * 8];                    \
        _Pragma("unroll")                                             \
        for (int s_ = 0; s_ < 7; ++s_)                                \
            if (s_ * 64 + lane < 396)                                 \
                GLDS(sp_ + bsrc[s_], lb_ + s_ * 512);                 \
    }

    // prologue
    STAGE(0);
    asm volatile("s_waitcnt vmcnt(0)" ::: "memory");
    __builtin_amdgcn_s_barrier();

    for (int ch = 0; ch < 8; ++ch) {
        if (ch < 7) STAGE(ch + 1);
        const ushort* buf = Bb[ch & 1];
        // A base for tap 0 of this chunk: [ch][t][kbq=hi][co0+l31][e8]
        const short* wp = W2 + (size_t)(ch * 9 * 4 * 256) * 8 + (size_t)(hi * 256 + co0 + l31) * 8;
#pragma unroll
        for (int t = 0; t < 9; ++t) {
            const int kh = t / 3, kw = t - kh * 3;
            // A frags: a[a][k2], kbq = k2*2 + hi
            short8 a00 = *(const short8*)(wp);                       // a=0 k2=0
            short8 a01 = *(const short8*)(wp + 32 * 8);              // a=1 k2=0
            short8 a10 = *(const short8*)(wp + 2 * 256 * 8);         // a=0 k2=1
            short8 a11 = *(const short8*)(wp + 2 * 256 * 8 + 32 * 8);

            // B frags: granule (r*4 + k2*2 + hi)*66 + kw + l31 + f*32
            const int gb = ((wv + kh) * 4 + hi) * 66 + kw + l31;
            short8 b00 = *(const short8*)&buf[(size_t)gb * 8];           // f=0 k2=0
            short8 b01 = *(const short8*)&buf[(size_t)(gb + 32) * 8];    // f=1 k2=0
            short8 b10 = *(const short8*)&buf[(size_t)(gb + 132) * 8];   // f=0 k2=1
            short8 b11 = *(const short8*)&buf[(size_t)(gb + 164) * 8];   // f=1 k2=1

            __builtin_amdgcn_s_setprio(1);
            acc[0][0] = __builtin_amdgcn_mfma_f32_32x32x16_bf16(a00, b00, acc[0][0], 0, 0, 0);
            acc[0][1] = __builtin_amdgcn_mfma_f32_32x32x16_bf16(a00, b01, acc[0][1], 0, 0, 0);
            acc[1][0] = __builtin_amdgcn_mfma_f32_32x32x16_bf16(a01, b00, acc[1][0], 0, 0, 0);
            acc[1][1] = __builtin_amdgcn_mfma_f32_32x32x16_bf16(a01, b01, acc[1][1], 0, 0, 0);
            acc[0][0] = __builtin_amdgcn_mfma_f32_32x32x16_bf16(a10, b10, acc[0][0], 0, 0, 0);
            acc[0][1] = __builtin_amdgcn_mfma_f32_32x32x16_bf16(a10, b11, acc[0][1], 0, 0, 0);
            acc[1][0] = __builtin_amdgcn_mfma_f32_32x32x16_bf16(a11, b10, acc[1][0], 0, 0, 0);
            acc[1][1] = __builtin_amdgcn_mfma_f32_32x32x16_bf16(a11, b11, acc[1][1], 0, 0, 0);
            __builtin_amdgcn_s_setprio(0);

            wp += 4 * 256 * 8;  // next tap
        }
        // chunk end: stage(ch+1) landed; my LDS reads done; sync all waves
        asm volatile("s_waitcnt vmcnt(0) lgkmcnt(0)" ::: "memory");
        __builtin_amdgcn_s_barrier();
    }
#undef STAGE

    // epilogue: D col=lane&31 -> w, row=(j&3)+8*(j>>2)+4*hi -> co_local
    const int h = h0 + wv;
#pragma unroll
    for (int a = 0; a < 2; ++a) {
#pragma unroll
        for (int f = 0; f < 2; ++f) {
            int w = f * 32 + l31;
            if (w < HW) {
#pragma unroll
                for (int j = 0; j < 16; ++j) {
                    int co = co0 + a * 32 + (j & 3) + 8 * (j >> 2) + 4 * hi;
                    out[(((size_t)b * CO + co) * HW + h) * HW + w] = acc[a][f][j];
                }
            }
        }
    }
}

// ---------------- Fallback (no-workspace path, round-2 verbatim) ----------------
__global__ __launch_bounds__(256, 2) void conv_mfma_fb(const float* __restrict__ x,
                                                       const short* __restrict__ W2,
                                                       float* __restrict__ out) {
    __shared__ __align__(16) short xs[6 * 72 * 32];

    const int tid  = threadIdx.x;
    const int lane = tid & 63;
    const int wv   = tid >> 6;
    const int l15  = lane & 15;
    const int kb   = lane >> 4;
    const int wm    = (wv >> 1) * 64;
    const int wnrow = (wv & 1) * 2;

    const int h0  = blockIdx.x * 4;
    const int co0 = blockIdx.y * 128;
    const int b   = blockIdx.z;

    f32x4 acc[4][8];
#pragma unroll
    for (int a = 0; a < 4; ++a)
#pragma unroll
        for (int f = 0; f < 8; ++f) acc[a][f] = (f32x4){0.f, 0.f, 0.f, 0.f};

    const float* xb = x + (size_t)b * CI * HW * HW;

    for (int ch = 0; ch < 8; ++ch) {
        const int ci0 = ch * 32;
        for (int f = tid; f < 6 * 66; f += 256) {
            int r = f / 66, c = f % 66;
            int h = h0 - 1 + r, wc = c - 1;
            bool valid = (h >= 0) & (h < HW) & (wc >= 0) & (wc < HW);
            const float* xsrc = xb + (size_t)ci0 * 3136 + (valid ? (h * HW + wc) : 0);
            int sw = (c >> 1) & 3;
            int sbase = (r * 72 + c) * 32;
#pragma unroll
            for (int k = 0; k < 4; ++k) {
                short8 pk;
#pragma unroll
                for (int e = 0; e < 8; ++e) {
                    float v = xsrc[(size_t)(k * 8 + e) * 3136];
                    pk[e] = (short)f2bf(valid ? v : 0.f);
                }
                *(short8*)&xs[sbase + ((k ^ sw) * 8)] = pk;
            }
        }
        __syncthreads();

#pragma unroll
        for (int kh = 0; kh < 3; ++kh) {
#pragma unroll
            for (int kw = 0; kw < 3; ++kw) {
                const int t = kh * 3 + kw;
                const short* ap = W2 + (size_t)((((ch * 9 + t) * 4 + kb) * 256) + co0 + wm + l15) * 8;
                short8 af[4];
#pragma unroll
                for (int a = 0; a < 4; ++a) af[a] = *(const short8*)(ap + a * 128);

                const int c0 = kw + l15;
                const int r0 = wnrow + kh;
                const short* bp = &xs[(r0 * 72 + c0) * 32 + ((kb ^ ((c0 >> 1) & 3)) * 8)];
                short8 bf[8];
#pragma unroll
                for (int f = 0; f < 8; ++f)
                    bf[f] = *(const short8*)(bp + (f >> 2) * 2304 + (f & 3) * 512);

#pragma unroll
                for (int a = 0; a < 4; ++a)
#pragma unroll
                    for (int f = 0; f < 8; ++f)
                        acc[a][f] = __builtin_amdgcn_mfma_f32_16x16x32_bf16(af[a], bf[f], acc[a][f], 0, 0, 0);
            }
        }
        __syncthreads();
    }

#pragma unroll
    for (int a = 0; a < 4; ++a) {
#pragma unroll
        for (int f = 0; f < 8; ++f) {
            int wloc = (f & 3) * 16 + l15;
            if (wloc < HW) {
                int h = h0 + wnrow + (f >> 2);
#pragma unroll
                for (int j = 0; j < 4; ++j) {
                    int cog = co0 + wm + 16 * a + kb * 4 + j;
                    out[(((size_t)b * CO + cog) * HW + h) * HW + wloc] = acc[a][f][j];
                }
            }
        }
    }
}

extern "C" void kernel_launch(void* const* d_in, const int* in_sizes, int n_in,
                              void* d_out, int out_size, void* d_ws, size_t ws_size,
                              hipStream_t stream) {
    const float* x       = (const float*)d_in[0]; // (32,256,56,56)
    const float* p_c     = (const float*)d_in[1]; // (256,256,3,3,7)
    const float* q_level = (const float*)d_in[2]; // (7,)
    float* out = (float*)d_out;

    short* W2 = (short*)d_ws;                          // 1.18 MB at offset 0
    const size_t XT_OFF = 2u * 1024 * 1024;
    const size_t need = XT_OFF + (size_t)32 * 3364 * 256 * 2;  // + 55.1 MB NHWC bf16

    quant_weights<<<(CO * CI * 9 + 255) / 256, 256, 0, stream>>>(p_c, q_level, W2);

    if (ws_size >= need) {
        ushort* xt_g = (ushort*)((char*)d_ws + XT_OFF);
        prep_main<<<dim3(56, 32), 256, 0, stream>>>(x, xt_g);
        conv32<<<dim3(14, 4, 32), 256, 0, stream>>>(xt_g, W2, out);
    } else {
        conv_mfma_fb<<<dim3(14, 2, 32), 256, 0, stream>>>(x, W2, out);
    }
}

// Round 8
// 184.720 us; speedup vs baseline: 1.1781x; 1.1781x over previous
//
#include <hip/hip_runtime.h>
#include <math.h>

#define CI   256
#define CO   256
#define HW   56
#define LQ   7
#define BETA 10.0f

typedef __attribute__((ext_vector_type(8)))  short short8;
typedef __attribute__((ext_vector_type(4)))  float f32x4;

__device__ __forceinline__ ushort f2bf(float f) {
    uint u = __float_as_uint(f);
    u += 0x7FFF + ((u >> 16) & 1);
    return (ushort)(u >> 16);
}

#define GLDS(SRC, DST)                                                        \
    __builtin_amdgcn_global_load_lds(                                         \
        (const __attribute__((address_space(1))) void*)(SRC),                 \
        (__attribute__((address_space(3))) void*)(DST), 16, 0, 0)

// ---------------- Kernel 1: soft-quantize weights -> packed bf16 ----------------
// W2 layout: [chunk 8][tap 9][kb 4][co 256][e 8] bf16  (k = chunk*32 + kb*8 + e)
__global__ __launch_bounds__(256) void quant_weights(const float* __restrict__ p_c,
                                                     const float* __restrict__ q_level,
                                                     short* __restrict__ W2) {
    int idx = blockIdx.x * 256 + threadIdx.x;  // (co*256+ci)*9 + t
    if (idx >= CO * CI * 9) return;
    int coci = idx / 9;
    int t = idx - coci * 9;
    int co = coci >> 8, ci = coci & 255;
    const float* p = p_c + (size_t)idx * LQ;
    float pv[LQ];
    float ss = 0.f;
#pragma unroll
    for (int l = 0; l < LQ; ++l) { pv[l] = p[l]; ss += pv[l] * pv[l]; }
    float inv = rsqrtf(ss) * BETA;
    float m = -1e30f;
#pragma unroll
    for (int l = 0; l < LQ; ++l) { pv[l] *= inv; m = fmaxf(m, pv[l]); }
    float den = 0.f, num = 0.f;
#pragma unroll
    for (int l = 0; l < LQ; ++l) {
        float e = expf(pv[l] - m);
        den += e;
        num += e * q_level[l];
    }
    int widx = ((((ci >> 5) * 9 + t) * 4 + ((ci >> 3) & 3)) * 2048) + co * 8 + (ci & 7);
    W2[widx] = (short)f2bf(num / den);
}

// ---------------- Pre-pass: NCHW f32 -> padded NHWC bf16, border fused ----------------
__global__ __launch_bounds__(256) void prep_main(const float* __restrict__ x,
                                                 ushort* __restrict__ xt) {
    __shared__ ushort ld[256 * 60];
    const int tid = threadIdx.x;
    const int h = blockIdx.x;   // 0..55
    const int b = blockIdx.y;

    if (h == 0 || h == 55) {
        int rr = (h == 0) ? 0 : 57;
        size_t base = ((size_t)b * 58 + rr) * 58 * 256;
        uint4 z = {0, 0, 0, 0};
        for (int i = tid; i < 58 * 256 / 8; i += 256)
            *(uint4*)&xt[base + (size_t)i * 8] = z;
    }
    if (tid < 64) {
        int col = (tid >> 5) * 57;
        int chk = tid & 31;
        size_t o = (((size_t)b * 58 + h + 1) * 58 + col) * 256 + chk * 8;
        uint4 z = {0, 0, 0, 0};
        *(uint4*)&xt[o] = z;
    }

    const float* xp = x + ((size_t)b * CI) * 3136 + h * HW;
#pragma unroll
    for (int s = 0; s < 14; ++s) {
        int flat = s * 1024 + tid * 4;
        int ci = flat / 56;
        int w  = flat - ci * 56;
        const float4 v = *(const float4*)(xp + (size_t)ci * 3136 + w);
        ushort4 o;
        o.x = f2bf(v.x); o.y = f2bf(v.y); o.z = f2bf(v.z); o.w = f2bf(v.w);
        *(ushort4*)&ld[ci * 60 + w] = o;
    }
    __syncthreads();
    const int w = tid & 63;
    const int wq = tid >> 6;
    if (w < 56) {
        size_t obase = (((size_t)b * 58 + h + 1) * 58 + (w + 1)) * 256;
#pragma unroll
        for (int s = 0; s < 8; ++s) {
            int cig = s * 4 + wq;
            int base = (cig * 8) * 60 + w;
            uint u0 = (uint)ld[base]       | ((uint)ld[base + 60]  << 16);
            uint u1 = (uint)ld[base + 120] | ((uint)ld[base + 180] << 16);
            uint u2 = (uint)ld[base + 240] | ((uint)ld[base + 300] << 16);
            uint u3 = (uint)ld[base + 360] | ((uint)ld[base + 420] << 16);
            uint4 o = {u0, u1, u2, u3};
            *(uint4*)&xt[obase + cig * 8] = o;
        }
    }
}

// ---------------- Kernel 2: r3 structure + depth-1 A register prefetch ----------------
// 256 thr = 4 waves; block 128co x 256n (4h x 64w); wave 64co x 128n; 16x16x32 MFMA.
// Staging (B/x): glds double-buffer, swizzle on global source — r3 verbatim.
// NEW: A(t+1) prefetched into alternate reg pair during tap t (static af0/af1
// alternation; 9 taps odd -> per-chunk arg swap). vmcnt counts: chunk top = 7 staging
// + 1 in-flight A -> vmcnt(8); last chunk vmcnt(1).
__global__ __launch_bounds__(256, 2) void conv_pf(const ushort* __restrict__ xt_g,
                                                  const short* __restrict__ W2,
                                                  float* __restrict__ out) {
    __shared__ __align__(16) ushort Bb[2][12672];  // 2 x 25344 B

    const int tid  = threadIdx.x;
    const int lane = tid & 63;
    const int wv   = tid >> 6;
    const int l15  = lane & 15;
    const int kb   = lane >> 4;
    const int wm   = (wv >> 1) * 64;
    const int wn   = (wv & 1) * 2;

    const int h0  = blockIdx.x * 4;
    const int co0 = blockIdx.y * 128;
    const int b   = blockIdx.z;

    // B staging source offsets (1584 granules, 396/wave, 7 insts/wave/chunk)
    int bsrc[7];
#pragma unroll
    for (int s = 0; s < 7; ++s) {
        int gl = s * 64 + lane;
        int g  = wv * 396 + (gl < 396 ? gl : 0);
        int kbq = g & 3, pos = g >> 2;
        int r = pos / 66, c = pos - r * 66;
        int cc = c < 58 ? c : 57;
        int cig = kbq ^ ((c >> 1) & 3);     // swizzle on global source (m173)
        bsrc[s] = ((b * 58 + h0 + r) * 58 + cc) * 256 + cig * 8;
    }

    f32x4 acc[4][8];
#pragma unroll
    for (int a = 0; a < 4; ++a)
#pragma unroll
        for (int f = 0; f < 8; ++f) acc[a][f] = (f32x4){0.f, 0.f, 0.f, 0.f};

#define STAGE(CH)                                                     \
    {                                                                 \
        const ushort* sp_ = xt_g + (CH) * 32;                         \
        ushort* lb_ = &Bb[(CH) & 1][wv * 396 * 8];                    \
        _Pragma("unroll")                                             \
        for (int s_ = 0; s_ < 7; ++s_)                                \
            if (s_ * 64 + lane < 396)                                 \
                GLDS(sp_ + bsrc[s_], lb_ + s_ * 512);                 \
    }

#define LOADA(DST, G)                                                            \
    {                                                                            \
        const short* ap_ = W2 + (size_t)(G) * 8192                               \
                              + (size_t)(kb * 256 + co0 + wm + l15) * 8;         \
        DST[0] = *(const short8*)ap_;                                            \
        DST[1] = *(const short8*)(ap_ + 128);                                    \
        DST[2] = *(const short8*)(ap_ + 256);                                    \
        DST[3] = *(const short8*)(ap_ + 384);                                    \
    }

// tap T of chunk CH: read B frags, prefetch A(T+1) into NXT, 32 MFMA with CUR
#define TAP(CH, T, CUR, NXT)                                                     \
    {                                                                            \
        const int c0_ = ((T) % 3) + l15;                                         \
        const ushort* bp_ = &buf[(((wn + (T) / 3) * 66 + c0_) * 4                \
                                  + (kb ^ ((c0_ >> 1) & 3))) * 8];               \
        short8 bf_[8];                                                           \
        _Pragma("unroll")                                                        \
        for (int f_ = 0; f_ < 8; ++f_)                                           \
            bf_[f_] = *(const short8*)(bp_ + (f_ >> 2) * 2112 + (f_ & 3) * 512); \
        LOADA(NXT, ((CH) * 9 + (T) + 1 > 71) ? 71 : ((CH) * 9 + (T) + 1));       \
        _Pragma("unroll")                                                        \
        for (int a_ = 0; a_ < 4; ++a_)                                           \
            _Pragma("unroll")                                                    \
            for (int f_ = 0; f_ < 8; ++f_)                                       \
                acc[a_][f_] = __builtin_amdgcn_mfma_f32_16x16x32_bf16(           \
                    CUR[a_], bf_[f_], acc[a_][f_], 0, 0, 0);                     \
    }

// one chunk: AE = slot holding A(CH,0) on entry; exits with A(CH+1,0) in AO
#define CHUNK(CH, AE, AO)                                                        \
    {                                                                            \
        const ushort* buf = Bb[(CH) & 1];                                        \
        if ((CH) < 7) {                                                          \
            STAGE((CH) + 1);                                                     \
            asm volatile("s_waitcnt vmcnt(8)" ::: "memory");                     \
        } else {                                                                 \
            asm volatile("s_waitcnt vmcnt(1)" ::: "memory");                     \
        }                                                                        \
        __builtin_amdgcn_s_barrier();                                            \
        TAP(CH, 0, AE, AO) TAP(CH, 1, AO, AE) TAP(CH, 2, AE, AO)                 \
        TAP(CH, 3, AO, AE) TAP(CH, 4, AE, AO) TAP(CH, 5, AO, AE)                 \
        TAP(CH, 6, AE, AO) TAP(CH, 7, AO, AE) TAP(CH, 8, AE, AO)                 \
        asm volatile("s_waitcnt lgkmcnt(0)" ::: "memory");                       \
        __builtin_amdgcn_s_barrier();                                            \
    }

    short8 af0[4], af1[4];

    // prologue: stage chunk 0; load A(0,0)
    STAGE(0);
    LOADA(af0, 0);
    asm volatile("s_waitcnt vmcnt(0)" ::: "memory");
    __builtin_amdgcn_s_barrier();

    // 9 taps/chunk (odd) -> A-slot parity flips per chunk
    CHUNK(0, af0, af1)
    CHUNK(1, af1, af0)
    CHUNK(2, af0, af1)
    CHUNK(3, af1, af0)
    CHUNK(4, af0, af1)
    CHUNK(5, af1, af0)
    CHUNK(6, af0, af1)
    CHUNK(7, af1, af0)

#undef CHUNK
#undef TAP
#undef LOADA
#undef STAGE

    // ---- epilogue: D layout n=lane&15, m=(lane>>4)*4+j ----
#pragma unroll
    for (int a = 0; a < 4; ++a) {
#pragma unroll
        for (int f = 0; f < 8; ++f) {
            int wloc = (f & 3) * 16 + l15;
            if (wloc < HW) {
                int h = h0 + wn + (f >> 2);
#pragma unroll
                for (int j = 0; j < 4; ++j) {
                    int cog = co0 + wm + 16 * a + kb * 4 + j;
                    out[(((size_t)b * CO + cog) * HW + h) * HW + wloc] = acc[a][f][j];
                }
            }
        }
    }
}

// ---------------- Fallback (no-workspace path, round-2 verbatim) ----------------
__global__ __launch_bounds__(256, 2) void conv_mfma_fb(const float* __restrict__ x,
                                                       const short* __restrict__ W2,
                                                       float* __restrict__ out) {
    __shared__ __align__(16) short xs[6 * 72 * 32];

    const int tid  = threadIdx.x;
    const int lane = tid & 63;
    const int wv   = tid >> 6;
    const int l15  = lane & 15;
    const int kb   = lane >> 4;
    const int wm    = (wv >> 1) * 64;
    const int wnrow = (wv & 1) * 2;

    const int h0  = blockIdx.x * 4;
    const int co0 = blockIdx.y * 128;
    const int b   = blockIdx.z;

    f32x4 acc[4][8];
#pragma unroll
    for (int a = 0; a < 4; ++a)
#pragma unroll
        for (int f = 0; f < 8; ++f) acc[a][f] = (f32x4){0.f, 0.f, 0.f, 0.f};

    const float* xb = x + (size_t)b * CI * HW * HW;

    for (int ch = 0; ch < 8; ++ch) {
        const int ci0 = ch * 32;
        for (int f = tid; f < 6 * 66; f += 256) {
            int r = f / 66, c = f % 66;
            int h = h0 - 1 + r, wc = c - 1;
            bool valid = (h >= 0) & (h < HW) & (wc >= 0) & (wc < HW);
            const float* xsrc = xb + (size_t)ci0 * 3136 + (valid ? (h * HW + wc) : 0);
            int sw = (c >> 1) & 3;
            int sbase = (r * 72 + c) * 32;
#pragma unroll
            for (int k = 0; k < 4; ++k) {
                short8 pk;
#pragma unroll
                for (int e = 0; e < 8; ++e) {
                    float v = xsrc[(size_t)(k * 8 + e) * 3136];
                    pk[e] = (short)f2bf(valid ? v : 0.f);
                }
                *(short8*)&xs[sbase + ((k ^ sw) * 8)] = pk;
            }
        }
        __syncthreads();

#pragma unroll
        for (int kh = 0; kh < 3; ++kh) {
#pragma unroll
            for (int kw = 0; kw < 3; ++kw) {
                const int t = kh * 3 + kw;
                const short* ap = W2 + (size_t)((((ch * 9 + t) * 4 + kb) * 256) + co0 + wm + l15) * 8;
                short8 af[4];
#pragma unroll
                for (int a = 0; a < 4; ++a) af[a] = *(const short8*)(ap + a * 128);

                const int c0 = kw + l15;
                const int r0 = wnrow + kh;
                const short* bp = &xs[(r0 * 72 + c0) * 32 + ((kb ^ ((c0 >> 1) & 3)) * 8)];
                short8 bf[8];
#pragma unroll
                for (int f = 0; f < 8; ++f)
                    bf[f] = *(const short8*)(bp + (f >> 2) * 2304 + (f & 3) * 512);

#pragma unroll
                for (int a = 0; a < 4; ++a)
#pragma unroll
                    for (int f = 0; f < 8; ++f)
                        acc[a][f] = __builtin_amdgcn_mfma_f32_16x16x32_bf16(af[a], bf[f], acc[a][f], 0, 0, 0);
            }
        }
        __syncthreads();
    }

#pragma unroll
    for (int a = 0; a < 4; ++a) {
#pragma unroll
        for (int f = 0; f < 8; ++f) {
            int wloc = (f & 3) * 16 + l15;
            if (wloc < HW) {
                int h = h0 + wnrow + (f >> 2);
#pragma unroll
                for (int j = 0; j < 4; ++j) {
                    int cog = co0 + wm + 16 * a + kb * 4 + j;
                    out[(((size_t)b * CO + cog) * HW + h) * HW + wloc] = acc[a][f][j];
                }
            }
        }
    }
}

extern "C" void kernel_launch(void* const* d_in, const int* in_sizes, int n_in,
                              void* d_out, int out_size, void* d_ws, size_t ws_size,
                              hipStream_t stream) {
    const float* x       = (const float*)d_in[0]; // (32,256,56,56)
    const float* p_c     = (const float*)d_in[1]; // (256,256,3,3,7)
    const float* q_level = (const float*)d_in[2]; // (7,)
    float* out = (float*)d_out;

    short* W2 = (short*)d_ws;                          // 1.18 MB at offset 0
    const size_t XT_OFF = 2u * 1024 * 1024;
    const size_t need = XT_OFF + (size_t)32 * 3364 * 256 * 2;  // + 55.1 MB NHWC bf16

    quant_weights<<<(CO * CI * 9 + 255) / 256, 256, 0, stream>>>(p_c, q_level, W2);

    if (ws_size >= need) {
        ushort* xt_g = (ushort*)((char*)d_ws + XT_OFF);
        prep_main<<<dim3(56, 32), 256, 0, stream>>>(x, xt_g);
        conv_pf<<<dim3(14, 2, 32), 256, 0, stream>>>(xt_g, W2, out);
    } else {
        conv_mfma_fb<<<dim3(14, 2, 32), 256, 0, stream>>>(x, W2, out);
    }
}

// Round 9
// 174.668 us; speedup vs baseline: 1.2459x; 1.0576x over previous
//
#include <hip/hip_runtime.h>
#include <math.h>

#define CI   256
#define CO   256
#define HW   56
#define LQ   7
#define BETA 10.0f

typedef __attribute__((ext_vector_type(8)))  short short8;
typedef __attribute__((ext_vector_type(4)))  float f32x4;

__device__ __forceinline__ ushort f2bf(float f) {
    uint u = __float_as_uint(f);
    u += 0x7FFF + ((u >> 16) & 1);
    return (ushort)(u >> 16);
}

#define GLDS(SRC, DST)                                                        \
    __builtin_amdgcn_global_load_lds(                                         \
        (const __attribute__((address_space(1))) void*)(SRC),                 \
        (__attribute__((address_space(3))) void*)(DST), 16, 0, 0)

// ---------------- Kernel 1: soft-quantize weights -> packed bf16 ----------------
// W2 layout: [chunk 8][tap 9][kb 4][co 256][e 8] bf16  (k = chunk*32 + kb*8 + e)
__global__ __launch_bounds__(256) void quant_weights(const float* __restrict__ p_c,
                                                     const float* __restrict__ q_level,
                                                     short* __restrict__ W2) {
    int idx = blockIdx.x * 256 + threadIdx.x;  // (co*256+ci)*9 + t
    if (idx >= CO * CI * 9) return;
    int coci = idx / 9;
    int t = idx - coci * 9;
    int co = coci >> 8, ci = coci & 255;
    const float* p = p_c + (size_t)idx * LQ;
    float pv[LQ];
    float ss = 0.f;
#pragma unroll
    for (int l = 0; l < LQ; ++l) { pv[l] = p[l]; ss += pv[l] * pv[l]; }
    float inv = rsqrtf(ss) * BETA;
    float m = -1e30f;
#pragma unroll
    for (int l = 0; l < LQ; ++l) { pv[l] *= inv; m = fmaxf(m, pv[l]); }
    float den = 0.f, num = 0.f;
#pragma unroll
    for (int l = 0; l < LQ; ++l) {
        float e = expf(pv[l] - m);
        den += e;
        num += e * q_level[l];
    }
    int widx = ((((ci >> 5) * 9 + t) * 4 + ((ci >> 3) & 3)) * 2048) + co * 8 + (ci & 7);
    W2[widx] = (short)f2bf(num / den);
}

// ---------------- Pre-pass: NCHW f32 -> padded "NC8HW8" bf16, border fused ----------------
// x_t layout: [b 32][cig 32][hh 58][ww 58][e 8] bf16
//   x_t[b][cig][h+1][w+1][e] = bf16(x[b][cig*8+e][h][w]); border granules = 0.
// Granule row stride = 58*8 = 464 ushorts; cig stride = 58*58*8 = 26912 ushorts.
// Phase-2 lanes (=w) write CONSECUTIVE 16B granules -> fully coalesced 1KB/wave stores.
__global__ __launch_bounds__(256) void prep_main(const float* __restrict__ x,
                                                 ushort* __restrict__ xt) {
    __shared__ ushort ld[256 * 60];
    const int tid = threadIdx.x;
    const int h = blockIdx.x;   // 0..55
    const int b = blockIdx.y;
    const uint4 z = {0, 0, 0, 0};

    // fused border zeroing: rows 0/57 (edge blocks), cols 0/57 of row h+1
    if (h == 0 || h == 55) {
        int rr = (h == 0) ? 0 : 57;
        for (int i = tid; i < 32 * 58; i += 256) {
            int cig = i / 58, w = i - cig * 58;
            *(uint4*)&xt[(((size_t)b * 32 + cig) * 58 + rr) * 464 + w * 8] = z;
        }
    }
    if (tid < 64) {
        int col = (tid >> 5) * 57;
        int chk = tid & 31;
        *(uint4*)&xt[(((size_t)b * 32 + chk) * 58 + h + 1) * 464 + col * 8] = z;
    }

    // phase 1: read x row h (all 256 ci), cvt, stash [ci][w] in LDS
    const float* xp = x + ((size_t)b * CI) * 3136 + h * HW;
#pragma unroll
    for (int s = 0; s < 14; ++s) {
        int flat = s * 1024 + tid * 4;  // 256*56 elems, 14 steps exact
        int ci = flat / 56;
        int w  = flat - ci * 56;
        const float4 v = *(const float4*)(xp + (size_t)ci * 3136 + w);
        ushort4 o;
        o.x = f2bf(v.x); o.y = f2bf(v.y); o.z = f2bf(v.z); o.w = f2bf(v.w);
        *(ushort4*)&ld[ci * 60 + w] = o;
    }
    __syncthreads();

    // phase 2: lane = w (conflict-free LDS reads); store 16B granules, lanes consecutive
    const int w = tid & 63;
    const int wq = tid >> 6;
    if (w < 56) {
#pragma unroll
        for (int s = 0; s < 8; ++s) {
            int cig = s * 4 + wq;
            int base = (cig * 8) * 60 + w;
            uint u0 = (uint)ld[base]       | ((uint)ld[base + 60]  << 16);
            uint u1 = (uint)ld[base + 120] | ((uint)ld[base + 180] << 16);
            uint u2 = (uint)ld[base + 240] | ((uint)ld[base + 300] << 16);
            uint u3 = (uint)ld[base + 360] | ((uint)ld[base + 420] << 16);
            uint4 o = {u0, u1, u2, u3};
            *(uint4*)&xt[(((size_t)b * 32 + cig) * 58 + h + 1) * 464 + (w + 1) * 8] = o;
        }
    }
}

// ---------------- Kernel 2: implicit-GEMM conv (r3 structure, verbatim sync) ----------------
// 256 thr = 4 waves; block 128co x 256n (4h x 64w); wave 64co x 128n; 16x16x32 MFMA.
// glds double-buffer staging; swizzle applied on the global SOURCE address; LDS
// layout/content and all read patterns identical to the proven 139us/0-conflict r3.
// Only the bsrc formula changed for the new x_t layout.
__global__ __launch_bounds__(256, 2) void conv_mfma2(const ushort* __restrict__ xt_g,
                                                     const short* __restrict__ W2,
                                                     float* __restrict__ out) {
    __shared__ __align__(16) ushort Bb[2][12672];  // 2 x 25344 B

    const int tid  = threadIdx.x;
    const int lane = tid & 63;
    const int wv   = tid >> 6;
    const int l15  = lane & 15;
    const int kb   = lane >> 4;
    const int wm   = (wv >> 1) * 64;
    const int wn   = (wv & 1) * 2;

    const int h0  = blockIdx.x * 4;
    const int co0 = blockIdx.y * 128;
    const int b   = blockIdx.z;

    // staging source offsets: granule gg=(r*66+c)*4+kbq holds
    //   x_t[b][ch*4 + (kbq ^ ((c>>1)&3))][h0+r][min(c,57)][0..8)
    int bsrc[7];
#pragma unroll
    for (int s = 0; s < 7; ++s) {
        int gl = s * 64 + lane;
        int g  = wv * 396 + (gl < 396 ? gl : 0);
        int kbq = g & 3, pos = g >> 2;
        int r = pos / 66, c = pos - r * 66;
        int cc = c < 58 ? c : 57;
        int cigx = kbq ^ ((c >> 1) & 3);   // swizzle on global source (m173)
        bsrc[s] = ((b * 32 + cigx) * 58 + h0 + r) * 464 + cc * 8;
    }

    f32x4 acc[4][8];
#pragma unroll
    for (int a = 0; a < 4; ++a)
#pragma unroll
        for (int f = 0; f < 8; ++f) acc[a][f] = (f32x4){0.f, 0.f, 0.f, 0.f};

#define STAGE(CH)                                                     \
    {                                                                 \
        const ushort* sp_ = xt_g + (size_t)(CH) * 107648;             \
        ushort* lb_ = &Bb[(CH) & 1][wv * 396 * 8];                    \
        _Pragma("unroll")                                             \
        for (int s_ = 0; s_ < 7; ++s_)                                \
            if (s_ * 64 + lane < 396)                                 \
                GLDS(sp_ + bsrc[s_], lb_ + s_ * 512);                 \
    }

    // prologue: stage chunk 0 into buf 0
    STAGE(0);

    for (int ch = 0; ch < 8; ++ch) {
        if (ch < 7) {  // stage next chunk into other buffer (overlaps compute)
            STAGE(ch + 1);
            asm volatile("s_waitcnt vmcnt(7)" ::: "memory");  // chunk ch landed
        } else {
            asm volatile("s_waitcnt vmcnt(0)" ::: "memory");
        }
        __builtin_amdgcn_s_barrier();

        const ushort* buf = Bb[ch & 1];
#pragma unroll
        for (int kh = 0; kh < 3; ++kh) {
#pragma unroll
            for (int kw = 0; kw < 3; ++kw) {
                const int t = kh * 3 + kw;
                const short* ap = W2 + (size_t)(((ch * 9 + t) * 4 + kb) * 256 + co0 + wm + l15) * 8;
                short8 af[4];
#pragma unroll
                for (int a = 0; a < 4; ++a) af[a] = *(const short8*)(ap + a * 128);

                const int c0 = kw + l15;
                const int r0 = wn + kh;
                const ushort* bp = &buf[((r0 * 66 + c0) * 4 + (kb ^ ((c0 >> 1) & 3))) * 8];
                short8 bf[8];
#pragma unroll
                for (int f = 0; f < 8; ++f)
                    bf[f] = *(const short8*)(bp + (f >> 2) * 2112 + (f & 3) * 512);

#pragma unroll
                for (int a = 0; a < 4; ++a)
#pragma unroll
                    for (int f = 0; f < 8; ++f)
                        acc[a][f] = __builtin_amdgcn_mfma_f32_16x16x32_bf16(af[a], bf[f], acc[a][f], 0, 0, 0);
            }
        }
        asm volatile("s_waitcnt lgkmcnt(0)" ::: "memory");  // my LDS reads done
        __builtin_amdgcn_s_barrier();                       // all waves done reading
    }
#undef STAGE

    // ---- epilogue: D layout n=lane&15, m=(lane>>4)*4+j ----
#pragma unroll
    for (int a = 0; a < 4; ++a) {
#pragma unroll
        for (int f = 0; f < 8; ++f) {
            int wloc = (f & 3) * 16 + l15;
            if (wloc < HW) {
                int h = h0 + wn + (f >> 2);
#pragma unroll
                for (int j = 0; j < 4; ++j) {
                    int cog = co0 + wm + 16 * a + kb * 4 + j;
                    out[(((size_t)b * CO + cog) * HW + h) * HW + wloc] = acc[a][f][j];
                }
            }
        }
    }
}

// ---------------- Fallback (no-workspace path, round-2 verbatim) ----------------
__global__ __launch_bounds__(256, 2) void conv_mfma_fb(const float* __restrict__ x,
                                                       const short* __restrict__ W2,
                                                       float* __restrict__ out) {
    __shared__ __align__(16) short xs[6 * 72 * 32];

    const int tid  = threadIdx.x;
    const int lane = tid & 63;
    const int wv   = tid >> 6;
    const int l15  = lane & 15;
    const int kb   = lane >> 4;
    const int wm    = (wv >> 1) * 64;
    const int wnrow = (wv & 1) * 2;

    const int h0  = blockIdx.x * 4;
    const int co0 = blockIdx.y * 128;
    const int b   = blockIdx.z;

    f32x4 acc[4][8];
#pragma unroll
    for (int a = 0; a < 4; ++a)
#pragma unroll
        for (int f = 0; f < 8; ++f) acc[a][f] = (f32x4){0.f, 0.f, 0.f, 0.f};

    const float* xb = x + (size_t)b * CI * HW * HW;

    for (int ch = 0; ch < 8; ++ch) {
        const int ci0 = ch * 32;
        for (int f = tid; f < 6 * 66; f += 256) {
            int r = f / 66, c = f % 66;
            int h = h0 - 1 + r, wc = c - 1;
            bool valid = (h >= 0) & (h < HW) & (wc >= 0) & (wc < HW);
            const float* xsrc = xb + (size_t)ci0 * 3136 + (valid ? (h * HW + wc) : 0);
            int sw = (c >> 1) & 3;
            int sbase = (r * 72 + c) * 32;
#pragma unroll
            for (int k = 0; k < 4; ++k) {
                short8 pk;
#pragma unroll
                for (int e = 0; e < 8; ++e) {
                    float v = xsrc[(size_t)(k * 8 + e) * 3136];
                    pk[e] = (short)f2bf(valid ? v : 0.f);
                }
                *(short8*)&xs[sbase + ((k ^ sw) * 8)] = pk;
            }
        }
        __syncthreads();

#pragma unroll
        for (int kh = 0; kh < 3; ++kh) {
#pragma unroll
            for (int kw = 0; kw < 3; ++kw) {
                const int t = kh * 3 + kw;
                const short* ap = W2 + (size_t)((((ch * 9 + t) * 4 + kb) * 256) + co0 + wm + l15) * 8;
                short8 af[4];
#pragma unroll
                for (int a = 0; a < 4; ++a) af[a] = *(const short8*)(ap + a * 128);

                const int c0 = kw + l15;
                const int r0 = wnrow + kh;
                const short* bp = &xs[(r0 * 72 + c0) * 32 + ((kb ^ ((c0 >> 1) & 3)) * 8)];
                short8 bf[8];
#pragma unroll
                for (int f = 0; f < 8; ++f)
                    bf[f] = *(const short8*)(bp + (f >> 2) * 2304 + (f & 3) * 512);

#pragma unroll
                for (int a = 0; a < 4; ++a)
#pragma unroll
                    for (int f = 0; f < 8; ++f)
                        acc[a][f] = __builtin_amdgcn_mfma_f32_16x16x32_bf16(af[a], bf[f], acc[a][f], 0, 0, 0);
            }
        }
        __syncthreads();
    }

#pragma unroll
    for (int a = 0; a < 4; ++a) {
#pragma unroll
        for (int f = 0; f < 8; ++f) {
            int wloc = (f & 3) * 16 + l15;
            if (wloc < HW) {
                int h = h0 + wnrow + (f >> 2);
#pragma unroll
                for (int j = 0; j < 4; ++j) {
                    int cog = co0 + wm + 16 * a + kb * 4 + j;
                    out[(((size_t)b * CO + cog) * HW + h) * HW + wloc] = acc[a][f][j];
                }
            }
        }
    }
}

extern "C" void kernel_launch(void* const* d_in, const int* in_sizes, int n_in,
                              void* d_out, int out_size, void* d_ws, size_t ws_size,
                              hipStream_t stream) {
    const float* x       = (const float*)d_in[0]; // (32,256,56,56)
    const float* p_c     = (const float*)d_in[1]; // (256,256,3,3,7)
    const float* q_level = (const float*)d_in[2]; // (7,)
    float* out = (float*)d_out;

    short* W2 = (short*)d_ws;                          // 1.18 MB at offset 0
    const size_t XT_OFF = 2u * 1024 * 1024;
    const size_t need = XT_OFF + (size_t)32 * 32 * 58 * 58 * 8 * 2;  // + 55.1 MB bf16

    quant_weights<<<(CO * CI * 9 + 255) / 256, 256, 0, stream>>>(p_c, q_level, W2);

    if (ws_size >= need) {
        ushort* xt_g = (ushort*)((char*)d_ws + XT_OFF);
        prep_main<<<dim3(56, 32), 256, 0, stream>>>(x, xt_g);
        conv_mfma2<<<dim3(14, 2, 32), 256, 0, stream>>>(xt_g, W2, out);
    } else {
        conv_mfma_fb<<<dim3(14, 2, 32), 256, 0, stream>>>(x, W2, out);
    }
}

// Round 10
// 173.229 us; speedup vs baseline: 1.2563x; 1.0083x over previous
//
#include <hip/hip_runtime.h>
#include <math.h>

#define CI   256
#define CO   256
#define HW   56
#define LQ   7
#define BETA 10.0f

typedef __attribute__((ext_vector_type(8)))  short short8;
typedef __attribute__((ext_vector_type(4)))  float f32x4;

__device__ __forceinline__ ushort f2bf(float f) {
    uint u = __float_as_uint(f);
    u += 0x7FFF + ((u >> 16) & 1);
    return (ushort)(u >> 16);
}

#define GLDS(SRC, DST)                                                        \
    __builtin_amdgcn_global_load_lds(                                         \
        (const __attribute__((address_space(1))) void*)(SRC),                 \
        (__attribute__((address_space(3))) void*)(DST), 16, 0, 0)

// ---------------- Kernel 1: soft-quantize weights -> packed bf16 ----------------
// W2 layout: [chunk 8][tap 9][kb 4][co 256][e 8] bf16  (k = chunk*32 + kb*8 + e)
__global__ __launch_bounds__(256) void quant_weights(const float* __restrict__ p_c,
                                                     const float* __restrict__ q_level,
                                                     short* __restrict__ W2) {
    int idx = blockIdx.x * 256 + threadIdx.x;  // (co*256+ci)*9 + t
    if (idx >= CO * CI * 9) return;
    int coci = idx / 9;
    int t = idx - coci * 9;
    int co = coci >> 8, ci = coci & 255;
    const float* p = p_c + (size_t)idx * LQ;
    float pv[LQ];
    float ss = 0.f;
#pragma unroll
    for (int l = 0; l < LQ; ++l) { pv[l] = p[l]; ss += pv[l] * pv[l]; }
    float inv = rsqrtf(ss) * BETA;
    float m = -1e30f;
#pragma unroll
    for (int l = 0; l < LQ; ++l) { pv[l] *= inv; m = fmaxf(m, pv[l]); }
    float den = 0.f, num = 0.f;
#pragma unroll
    for (int l = 0; l < LQ; ++l) {
        float e = __expf(pv[l] - m);
        den += e;
        num += e * q_level[l];
    }
    int widx = ((((ci >> 5) * 9 + t) * 4 + ((ci >> 3) & 3)) * 2048) + co * 8 + (ci & 7);
    W2[widx] = (short)f2bf(num / den);
}

// ---------------- Pre-pass: NCHW f32 -> padded "NC8HW8" bf16, border fused ----------------
// x_t layout: [b 32][cig 32][hh 58][ww 58][e 8] bf16
__global__ __launch_bounds__(256) void prep_main(const float* __restrict__ x,
                                                 ushort* __restrict__ xt) {
    __shared__ ushort ld[256 * 60];
    const int tid = threadIdx.x;
    const int h = blockIdx.x;   // 0..55
    const int b = blockIdx.y;
    const uint4 z = {0, 0, 0, 0};

    if (h == 0 || h == 55) {
        int rr = (h == 0) ? 0 : 57;
        for (int i = tid; i < 32 * 58; i += 256) {
            int cig = i / 58, w = i - cig * 58;
            *(uint4*)&xt[(((size_t)b * 32 + cig) * 58 + rr) * 464 + w * 8] = z;
        }
    }
    if (tid < 64) {
        int col = (tid >> 5) * 57;
        int chk = tid & 31;
        *(uint4*)&xt[(((size_t)b * 32 + chk) * 58 + h + 1) * 464 + col * 8] = z;
    }

    const float* xp = x + ((size_t)b * CI) * 3136 + h * HW;
#pragma unroll
    for (int s = 0; s < 14; ++s) {
        int flat = s * 1024 + tid * 4;
        int ci = flat / 56;
        int w  = flat - ci * 56;
        const float4 v = *(const float4*)(xp + (size_t)ci * 3136 + w);
        ushort4 o;
        o.x = f2bf(v.x); o.y = f2bf(v.y); o.z = f2bf(v.z); o.w = f2bf(v.w);
        *(ushort4*)&ld[ci * 60 + w] = o;
    }
    __syncthreads();

    const int w = tid & 63;
    const int wq = tid >> 6;
    if (w < 56) {
#pragma unroll
        for (int s = 0; s < 8; ++s) {
            int cig = s * 4 + wq;
            int base = (cig * 8) * 60 + w;
            uint u0 = (uint)ld[base]       | ((uint)ld[base + 60]  << 16);
            uint u1 = (uint)ld[base + 120] | ((uint)ld[base + 180] << 16);
            uint u2 = (uint)ld[base + 240] | ((uint)ld[base + 300] << 16);
            uint u3 = (uint)ld[base + 360] | ((uint)ld[base + 420] << 16);
            uint4 o = {u0, u1, u2, u3};
            *(uint4*)&xt[(((size_t)b * 32 + cig) * 58 + h + 1) * 464 + (w + 1) * 8] = o;
        }
    }
}

// ---------------- Kernel 2: implicit-GEMM conv (r3/r9 structure, verbatim sync) ----------------
// 256 thr = 4 waves; block 128co x 256n (4h x 64w); wave 64co x 128n; 16x16x32 MFMA.
// NEW (T1): 1D grid 896 with XCD pair-swizzle decode — blocks (x,y=0,z) and
// (x,y=1,z) differ by 448 in bid; 448%8==0 -> same bid%8 -> same XCD -> the
// shared 178KB x_t slab is fetched from HBM once and L2-hit by the partner.
__global__ __launch_bounds__(256, 2) void conv_mfma2(const ushort* __restrict__ xt_g,
                                                     const short* __restrict__ W2,
                                                     float* __restrict__ out) {
    __shared__ __align__(16) ushort Bb[2][12672];  // 2 x 25344 B

    const int tid  = threadIdx.x;
    const int lane = tid & 63;
    const int wv   = tid >> 6;
    const int l15  = lane & 15;
    const int kb   = lane >> 4;
    const int wm   = (wv >> 1) * 64;
    const int wn   = (wv & 1) * 2;

    const int bid = blockIdx.x;          // 0..895
    const int y   = bid / 448;           // co half
    const int P   = bid - y * 448;       // pair id; P%8 == bid%8 -> y-pair same XCD
    const int h0  = (P >> 5) * 4;
    const int b   = P & 31;
    const int co0 = y * 128;

    // staging source offsets: granule gg=(r*66+c)*4+kbq holds
    //   x_t[b][ch*4 + (kbq ^ ((c>>1)&3))][h0+r][min(c,57)][0..8)
    int bsrc[7];
#pragma unroll
    for (int s = 0; s < 7; ++s) {
        int gl = s * 64 + lane;
        int g  = wv * 396 + (gl < 396 ? gl : 0);
        int kbq = g & 3, pos = g >> 2;
        int r = pos / 66, c = pos - r * 66;
        int cc = c < 58 ? c : 57;
        int cigx = kbq ^ ((c >> 1) & 3);   // swizzle on global source (m173)
        bsrc[s] = ((b * 32 + cigx) * 58 + h0 + r) * 464 + cc * 8;
    }

    f32x4 acc[4][8];
#pragma unroll
    for (int a = 0; a < 4; ++a)
#pragma unroll
        for (int f = 0; f < 8; ++f) acc[a][f] = (f32x4){0.f, 0.f, 0.f, 0.f};

#define STAGE(CH)                                                     \
    {                                                                 \
        const ushort* sp_ = xt_g + (size_t)(CH) * 107648;             \
        ushort* lb_ = &Bb[(CH) & 1][wv * 396 * 8];                    \
        _Pragma("unroll")                                             \
        for (int s_ = 0; s_ < 7; ++s_)                                \
            if (s_ * 64 + lane < 396)                                 \
                GLDS(sp_ + bsrc[s_], lb_ + s_ * 512);                 \
    }

    STAGE(0);

    for (int ch = 0; ch < 8; ++ch) {
        if (ch < 7) {
            STAGE(ch + 1);
            asm volatile("s_waitcnt vmcnt(7)" ::: "memory");  // chunk ch landed
        } else {
            asm volatile("s_waitcnt vmcnt(0)" ::: "memory");
        }
        __builtin_amdgcn_s_barrier();

        const ushort* buf = Bb[ch & 1];
#pragma unroll
        for (int kh = 0; kh < 3; ++kh) {
#pragma unroll
            for (int kw = 0; kw < 3; ++kw) {
                const int t = kh * 3 + kw;
                const short* ap = W2 + (size_t)(((ch * 9 + t) * 4 + kb) * 256 + co0 + wm + l15) * 8;
                short8 af[4];
#pragma unroll
                for (int a = 0; a < 4; ++a) af[a] = *(const short8*)(ap + a * 128);

                const int c0 = kw + l15;
                const int r0 = wn + kh;
                const ushort* bp = &buf[((r0 * 66 + c0) * 4 + (kb ^ ((c0 >> 1) & 3))) * 8];
                short8 bf[8];
#pragma unroll
                for (int f = 0; f < 8; ++f)
                    bf[f] = *(const short8*)(bp + (f >> 2) * 2112 + (f & 3) * 512);

#pragma unroll
                for (int a = 0; a < 4; ++a)
#pragma unroll
                    for (int f = 0; f < 8; ++f)
                        acc[a][f] = __builtin_amdgcn_mfma_f32_16x16x32_bf16(af[a], bf[f], acc[a][f], 0, 0, 0);
            }
        }
        asm volatile("s_waitcnt lgkmcnt(0)" ::: "memory");
        __builtin_amdgcn_s_barrier();
    }
#undef STAGE

    // ---- epilogue: D layout n=lane&15, m=(lane>>4)*4+j ----
#pragma unroll
    for (int a = 0; a < 4; ++a) {
#pragma unroll
        for (int f = 0; f < 8; ++f) {
            int wloc = (f & 3) * 16 + l15;
            if (wloc < HW) {
                int h = h0 + wn + (f >> 2);
#pragma unroll
                for (int j = 0; j < 4; ++j) {
                    int cog = co0 + wm + 16 * a + kb * 4 + j;
                    out[(((size_t)b * CO + cog) * HW + h) * HW + wloc] = acc[a][f][j];
                }
            }
        }
    }
}

// ---------------- Fallback (no-workspace path, round-2 verbatim) ----------------
__global__ __launch_bounds__(256, 2) void conv_mfma_fb(const float* __restrict__ x,
                                                       const short* __restrict__ W2,
                                                       float* __restrict__ out) {
    __shared__ __align__(16) short xs[6 * 72 * 32];

    const int tid  = threadIdx.x;
    const int lane = tid & 63;
    const int wv   = tid >> 6;
    const int l15  = lane & 15;
    const int kb   = lane >> 4;
    const int wm    = (wv >> 1) * 64;
    const int wnrow = (wv & 1) * 2;

    const int h0  = blockIdx.x * 4;
    const int co0 = blockIdx.y * 128;
    const int b   = blockIdx.z;

    f32x4 acc[4][8];
#pragma unroll
    for (int a = 0; a < 4; ++a)
#pragma unroll
        for (int f = 0; f < 8; ++f) acc[a][f] = (f32x4){0.f, 0.f, 0.f, 0.f};

    const float* xb = x + (size_t)b * CI * HW * HW;

    for (int ch = 0; ch < 8; ++ch) {
        const int ci0 = ch * 32;
        for (int f = tid; f < 6 * 66; f += 256) {
            int r = f / 66, c = f % 66;
            int h = h0 - 1 + r, wc = c - 1;
            bool valid = (h >= 0) & (h < HW) & (wc >= 0) & (wc < HW);
            const float* xsrc = xb + (size_t)ci0 * 3136 + (valid ? (h * HW + wc) : 0);
            int sw = (c >> 1) & 3;
            int sbase = (r * 72 + c) * 32;
#pragma unroll
            for (int k = 0; k < 4; ++k) {
                short8 pk;
#pragma unroll
                for (int e = 0; e < 8; ++e) {
                    float v = xsrc[(size_t)(k * 8 + e) * 3136];
                    pk[e] = (short)f2bf(valid ? v : 0.f);
                }
                *(short8*)&xs[sbase + ((k ^ sw) * 8)] = pk;
            }
        }
        __syncthreads();

#pragma unroll
        for (int kh = 0; kh < 3; ++kh) {
#pragma unroll
            for (int kw = 0; kw < 3; ++kw) {
                const int t = kh * 3 + kw;
                const short* ap = W2 + (size_t)((((ch * 9 + t) * 4 + kb) * 256) + co0 + wm + l15) * 8;
                short8 af[4];
#pragma unroll
                for (int a = 0; a < 4; ++a) af[a] = *(const short8*)(ap + a * 128);

                const int c0 = kw + l15;
                const int r0 = wnrow + kh;
                const short* bp = &xs[(r0 * 72 + c0) * 32 + ((kb ^ ((c0 >> 1) & 3)) * 8)];
                short8 bf[8];
#pragma unroll
                for (int f = 0; f < 8; ++f)
                    bf[f] = *(const short8*)(bp + (f >> 2) * 2304 + (f & 3) * 512);

#pragma unroll
                for (int a = 0; a < 4; ++a)
#pragma unroll
                    for (int f = 0; f < 8; ++f)
                        acc[a][f] = __builtin_amdgcn_mfma_f32_16x16x32_bf16(af[a], bf[f], acc[a][f], 0, 0, 0);
            }
        }
        __syncthreads();
    }

#pragma unroll
    for (int a = 0; a < 4; ++a) {
#pragma unroll
        for (int f = 0; f < 8; ++f) {
            int wloc = (f & 3) * 16 + l15;
            if (wloc < HW) {
                int h = h0 + wnrow + (f >> 2);
#pragma unroll
                for (int j = 0; j < 4; ++j) {
                    int cog = co0 + wm + 16 * a + kb * 4 + j;
                    out[(((size_t)b * CO + cog) * HW + h) * HW + wloc] = acc[a][f][j];
                }
            }
        }
    }
}

extern "C" void kernel_launch(void* const* d_in, const int* in_sizes, int n_in,
                              void* d_out, int out_size, void* d_ws, size_t ws_size,
                              hipStream_t stream) {
    const float* x       = (const float*)d_in[0]; // (32,256,56,56)
    const float* p_c     = (const float*)d_in[1]; // (256,256,3,3,7)
    const float* q_level = (const float*)d_in[2]; // (7,)
    float* out = (float*)d_out;

    short* W2 = (short*)d_ws;                          // 1.18 MB at offset 0
    const size_t XT_OFF = 2u * 1024 * 1024;
    const size_t need = XT_OFF + (size_t)32 * 32 * 58 * 58 * 8 * 2;  // + 55.1 MB bf16

    quant_weights<<<(CO * CI * 9 + 255) / 256, 256, 0, stream>>>(p_c, q_level, W2);

    if (ws_size >= need) {
        ushort* xt_g = (ushort*)((char*)d_ws + XT_OFF);
        prep_main<<<dim3(56, 32), 256, 0, stream>>>(x, xt_g);
        conv_mfma2<<<dim3(896), 256, 0, stream>>>(xt_g, W2, out);
    } else {
        conv_mfma_fb<<<dim3(14, 2, 32), 256, 0, stream>>>(x, W2, out);
    }
}